// Round 6
// baseline (331.471 us; speedup 1.0000x reference)
//
#include <hip/hip_runtime.h>
#include <hip/hip_bf16.h>
#include <stdint.h>

#define N_TOK 4096
#define CDIM 768
#define NH 12
#define HD 64
#define SX (N_TOK * CDIM)
#define SW (CDIM * CDIM)

typedef __attribute__((ext_vector_type(8))) short bf16x8;
typedef __attribute__((ext_vector_type(4))) float f32x4;
typedef unsigned short ushort_t;
typedef unsigned int uint_t;

typedef const __attribute__((address_space(1))) void* as1_cvp;
typedef __attribute__((address_space(3))) void* as3_vp;
#define GLD16(g, s) __builtin_amdgcn_global_load_lds((as1_cvp)(g), (as3_vp)(s), 16, 0, 0)

__device__ inline ushort_t f2bf(float f) {
    union { float f; uint_t u; } c; c.f = f;
    uint_t u = (c.u + 0x7FFFu + ((c.u >> 16) & 1u)) >> 16;
    return (ushort_t)u;
}
__device__ inline uint_t pack_bf2(float a, float b) {
    union { __hip_bfloat162 v; uint_t u; } c;
    c.v = __float22bfloat162_rn(make_float2(a, b));
    return c.u;
}

// fp32 -> bf16 one-shot conversion of x, Wq|Wk|Wv (concat), Wo; bq|bk|bv concat fp32.
__global__ __launch_bounds__(256) void convert_all(
    const float* __restrict__ x,
    const float* __restrict__ Wq, const float* __restrict__ Wk,
    const float* __restrict__ Wv, const float* __restrict__ Wo,
    const float* __restrict__ bq, const float* __restrict__ bk, const float* __restrict__ bv,
    ushort_t* __restrict__ xb, ushort_t* __restrict__ Wf,
    ushort_t* __restrict__ Wob, float* __restrict__ biasf)
{
    long i = ((long)blockIdx.x * 256 + threadIdx.x) * 4;
    const float* src; ushort_t* dst; long off;
    if (i < SX)               { src = x;  dst = xb;          off = i; }
    else if (i < SX + SW)     { src = Wq; dst = Wf;          off = i - SX; }
    else if (i < SX + 2*SW)   { src = Wk; dst = Wf + SW;     off = i - SX - SW; }
    else if (i < SX + 3*SW)   { src = Wv; dst = Wf + 2*SW;   off = i - SX - 2*SW; }
    else if (i < SX + 4*SW)   { src = Wo; dst = Wob;         off = i - SX - 3*SW; }
    else if (i < SX + 4*SW + 3*CDIM) {
        long b = i - (SX + 4*SW);
        const float* bs = (b < CDIM) ? bq + b : (b < 2*CDIM) ? bk + (b - CDIM) : bv + (b - 2*CDIM);
        *(float4*)(biasf + b) = *(const float4*)bs;
        return;
    } else return;
    float4 v4 = *(const float4*)(src + off);
    uint2 st = { pack_bf2(v4.x, v4.y), pack_bf2(v4.z, v4.w) };
    *(uint2*)(dst + off) = st;
}

// Fused QKV GEMM, m97-style: 128x128 tile, BK=64, global_load_lds(16B) into
// unpadded XOR-chunk-swizzled LDS. out[i][j] = sum_c xb[i][c]*Wf[j][c] + biasf[j].
// j<768 -> q, j<1536 -> k (row-major bf16); else v stored transposed vT[j][i].
__global__ __launch_bounds__(256) void gemm_qkv128(
    const ushort_t* __restrict__ xb, const ushort_t* __restrict__ Wf,
    const float* __restrict__ biasf,
    ushort_t* __restrict__ q, ushort_t* __restrict__ k, ushort_t* __restrict__ vT)
{
    __shared__ __align__(16) ushort_t Asm[128 * 64];
    __shared__ __align__(16) ushort_t Bsm[128 * 64];
    const int tid = threadIdx.x;
    const int w = tid >> 6, lane = tid & 63;
    const int quad = lane >> 4, l16 = lane & 15;
    const int row0 = blockIdx.x * 128;
    const int col0 = blockIdx.y * 128;
    const int rw = (w >> 1) * 64, cw = (w & 1) * 64;
    const int srow = lane >> 3;                   // 0..7 within staging call
    const int sc = ((lane & 7) ^ srow) * 8;       // swizzled col offset (elems)
    const int swz = l16 & 7;

    f32x4 acc[4][4];
#pragma unroll
    for (int a = 0; a < 4; a++)
#pragma unroll
        for (int b = 0; b < 4; b++) acc[a][b] = (f32x4){0.f, 0.f, 0.f, 0.f};

    for (int kc = 0; kc < CDIM; kc += 64) {
        __syncthreads();     // WAR: prior iter's ds_reads done
#pragma unroll
        for (int c = 0; c < 4; c++) {
            int ra = w * 32 + c * 8;
            GLD16(xb + (size_t)(row0 + ra + srow) * CDIM + kc + sc, &Asm[ra * 64]);
            GLD16(Wf + (size_t)(col0 + ra + srow) * CDIM + kc + sc, &Bsm[ra * 64]);
        }
        __syncthreads();     // staging visible (vmcnt drained before barrier)
#pragma unroll
        for (int kk = 0; kk < 2; kk++) {
            const int po = ((kk * 4 + quad) ^ swz) * 8;
            bf16x8 af[4], bfr[4];
#pragma unroll
            for (int rb = 0; rb < 4; rb++)
                af[rb] = *(const bf16x8*)&Asm[(rw + rb * 16 + l16) * 64 + po];
#pragma unroll
            for (int cb = 0; cb < 4; cb++)
                bfr[cb] = *(const bf16x8*)&Bsm[(cw + cb * 16 + l16) * 64 + po];
#pragma unroll
            for (int rb = 0; rb < 4; rb++)
#pragma unroll
                for (int cb = 0; cb < 4; cb++)
                    acc[rb][cb] = __builtin_amdgcn_mfma_f32_16x16x32_bf16(af[rb], bfr[cb], acc[rb][cb], 0, 0, 0);
        }
    }

    if (col0 < 2 * CDIM) {
        ushort_t* dst = (col0 < CDIM) ? q : k;
        const int jb0 = (col0 < CDIM) ? col0 : col0 - CDIM;
#pragma unroll
        for (int cb = 0; cb < 4; cb++) {
            int jg = cw + cb * 16 + l16;
            float bv_ = biasf[col0 + jg];
#pragma unroll
            for (int rb = 0; rb < 4; rb++)
#pragma unroll
                for (int r = 0; r < 4; r++) {
                    int i = row0 + rw + rb * 16 + quad * 4 + r;
                    dst[(size_t)i * CDIM + jb0 + jg] = f2bf(acc[rb][cb][r] + bv_);
                }
        }
    } else {
        // vT: two-pass 64x128 transpose through Asm (swizzled), coalesced stores
        const int jv0 = col0 - 2 * CDIM;
        ushort_t* T = Asm;
#pragma unroll
        for (int h = 0; h < 2; h++) {
            __syncthreads();
            if ((w & 1) == h) {
#pragma unroll
                for (int cb = 0; cb < 4; cb++) {
                    int jl = cb * 16 + l16;                    // 0..63 within half
                    float bv_ = biasf[col0 + h * 64 + jl];
#pragma unroll
                    for (int rb = 0; rb < 4; rb++)
#pragma unroll
                        for (int r = 0; r < 4; r++) {
                            int i = rw + rb * 16 + quad * 4 + r;   // 0..127
                            int cch = i >> 3, w8 = i & 7;
                            T[jl * 128 + ((cch ^ (jl & 7)) * 8) + w8] =
                                f2bf(acc[rb][cb][r] + bv_);
                        }
                }
            }
            __syncthreads();
#pragma unroll
            for (int p = 0; p < 4; p++) {
                int t = tid + p * 256, jl = t >> 4, i8 = t & 15;
                *(bf16x8*)(vT + (size_t)(jv0 + h * 64 + jl) * N_TOK + row0 + i8 * 8) =
                    *(const bf16x8*)&T[jl * 128 + ((i8 ^ (jl & 7)) * 8)];
            }
        }
    }
}

// Output projection: 128x64 tile, same m97 staging. fp32 out.
__global__ __launch_bounds__(256) void gemm_out128(
    const ushort_t* __restrict__ A, const ushort_t* __restrict__ W,
    const float* __restrict__ bias, float* __restrict__ out)
{
    __shared__ __align__(16) ushort_t Asm[128 * 64];
    __shared__ __align__(16) ushort_t Bsm[64 * 64];
    const int tid = threadIdx.x;
    const int w = tid >> 6, lane = tid & 63;
    const int quad = lane >> 4, l16 = lane & 15;
    const int row0 = blockIdx.x * 128;
    const int col0 = blockIdx.y * 64;
    const int rw = (w >> 1) * 64, cw = (w & 1) * 32;
    const int srow = lane >> 3;
    const int sc = ((lane & 7) ^ srow) * 8;
    const int swz = l16 & 7;

    f32x4 acc[4][2];
#pragma unroll
    for (int a = 0; a < 4; a++)
#pragma unroll
        for (int b = 0; b < 2; b++) acc[a][b] = (f32x4){0.f, 0.f, 0.f, 0.f};

    for (int kc = 0; kc < CDIM; kc += 64) {
        __syncthreads();
#pragma unroll
        for (int c = 0; c < 4; c++) {
            int ra = w * 32 + c * 8;
            GLD16(A + (size_t)(row0 + ra + srow) * CDIM + kc + sc, &Asm[ra * 64]);
        }
#pragma unroll
        for (int c = 0; c < 2; c++) {
            int rb_ = w * 16 + c * 8;
            GLD16(W + (size_t)(col0 + rb_ + srow) * CDIM + kc + sc, &Bsm[rb_ * 64]);
        }
        __syncthreads();
#pragma unroll
        for (int kk = 0; kk < 2; kk++) {
            const int po = ((kk * 4 + quad) ^ swz) * 8;
            bf16x8 af[4], bfr[2];
#pragma unroll
            for (int rb = 0; rb < 4; rb++)
                af[rb] = *(const bf16x8*)&Asm[(rw + rb * 16 + l16) * 64 + po];
#pragma unroll
            for (int cb = 0; cb < 2; cb++)
                bfr[cb] = *(const bf16x8*)&Bsm[(cw + cb * 16 + l16) * 64 + po];
#pragma unroll
            for (int rb = 0; rb < 4; rb++)
#pragma unroll
                for (int cb = 0; cb < 2; cb++)
                    acc[rb][cb] = __builtin_amdgcn_mfma_f32_16x16x32_bf16(af[rb], bfr[cb], acc[rb][cb], 0, 0, 0);
        }
    }
#pragma unroll
    for (int cb = 0; cb < 2; cb++) {
        int j = col0 + cw + cb * 16 + l16;
        float bv_ = bias[j];
#pragma unroll
        for (int rb = 0; rb < 4; rb++)
#pragma unroll
            for (int r = 0; r < 4; r++) {
                int i = row0 + rw + rb * 16 + quad * 4 + r;
                out[(size_t)i * CDIM + j] = acc[rb][cb][r] + bv_;
            }
    }
}

// Flash attention v2: S^T = K.Q^T (A=K from GLOBAL, B=Q from LDS); static-max
// softmax fully in-register (per-lane bias walk + per-lane l accumulation);
// P round-trips LDS as 4xb64 write / 4xb128 read (XOR-swizzled, unpadded);
// O = P.V with B=vT fragments from GLOBAL. K/vT register-prefetched 1 tile ahead.
__global__ __launch_bounds__(256, 3) void attn_kernel(
    const ushort_t* __restrict__ Q, const ushort_t* __restrict__ K,
    const ushort_t* __restrict__ VT, const int* __restrict__ sim,
    ushort_t* __restrict__ Oout)
{
    __shared__ __align__(16) ushort_t Qs[64][72];   // reused as O-tile at end
    __shared__ __align__(16) ushort_t P2[64 * 64];  // swizzled chunks of 8
    __shared__ int ssim[64][12];
    __shared__ float psum[2][64];
    __shared__ float linvLDS[64];

    const int tid = threadIdx.x;
    const int wave = tid >> 6, lane = tid & 63;
    const int quad = lane >> 4, l16 = lane & 15;
    const int wq = wave >> 1;     // j-half (S^T rows) and d-half (PV cols)
    const int wi = wave & 1;      // i-half (query columns of S^T)
    const int qbase = blockIdx.x * 64;
    const int hoff = blockIdx.y * HD;

    const float C1 = 0.18033688011112042f;   // 0.125 * log2(e)
    const float C2 = -11.541560327111707f;   // -8 * log2(e)

    // stage Q tile
#pragma unroll
    for (int p = 0; p < 2; p++) {
        int chunk = tid + p * 256, r = chunk >> 3, c8 = chunk & 7;
        *(bf16x8*)(&Qs[r][c8 * 8]) =
            *(const bf16x8*)(Q + (size_t)(qbase + r) * CDIM + hoff + c8 * 8);
    }
    // sort each row's 10 bias indices ascending
    if (tid < 64) {
        int vb_[10];
        const int* sp = sim + (size_t)(qbase + tid) * 10;
#pragma unroll
        for (int e = 0; e < 10; e++) vb_[e] = sp[e];
#pragma unroll
        for (int round = 0; round < 10; round++)
#pragma unroll
            for (int i = (round & 1); i + 1 < 10; i += 2) {
                int a = vb_[i], b = vb_[i + 1];
                vb_[i] = min(a, b); vb_[i + 1] = max(a, b);
            }
#pragma unroll
        for (int e = 0; e < 10; e++) ssim[tid][e] = vb_[e];
        ssim[tid][10] = 0x7FFFFFFF;
        ssim[tid][11] = 0x7FFFFFFF;
    }
    __syncthreads();

    const int rowi[2] = { wi * 32 + l16, wi * 32 + 16 + l16 };
    int curv[2], ptrv[2];
    float lsum[2] = { 0.f, 0.f };
#pragma unroll
    for (int ib = 0; ib < 2; ib++) { ptrv[ib] = 0; curv[ib] = ssim[rowi[ib]][0]; }

    f32x4 Oacc[2][2];
#pragma unroll
    for (int a = 0; a < 2; a++)
#pragma unroll
        for (int b = 0; b < 2; b++) Oacc[a][b] = (f32x4){0.f, 0.f, 0.f, 0.f};

    const int kcol = quad * 8;
    const int krow0 = wq * 32 + l16;

    // prefetch tile 0 fragments (K rows; vT rows)
    bf16x8 ka[2][2], vb[2][2];
#pragma unroll
    for (int jb = 0; jb < 2; jb++)
#pragma unroll
        for (int kk = 0; kk < 2; kk++) {
            ka[jb][kk] = *(const bf16x8*)(K + (size_t)(krow0 + jb * 16) * CDIM + hoff + kk * 32 + kcol);
            vb[jb][kk] = *(const bf16x8*)(VT + (size_t)(hoff + wq * 32 + jb * 16 + l16) * N_TOK + kk * 32 + kcol);
        }

    for (int j0 = 0; j0 < N_TOK; j0 += 64) {
        bf16x8 kc[2][2], vc[2][2];
#pragma unroll
        for (int jb = 0; jb < 2; jb++)
#pragma unroll
            for (int kk = 0; kk < 2; kk++) { kc[jb][kk] = ka[jb][kk]; vc[jb][kk] = vb[jb][kk]; }
        if (j0 + 64 < N_TOK) {
            const int jn = j0 + 64;
#pragma unroll
            for (int jb = 0; jb < 2; jb++)
#pragma unroll
                for (int kk = 0; kk < 2; kk++) {
                    ka[jb][kk] = *(const bf16x8*)(K + (size_t)(jn + krow0 + jb * 16) * CDIM + hoff + kk * 32 + kcol);
                    vb[jb][kk] = *(const bf16x8*)(VT + (size_t)(hoff + wq * 32 + jb * 16 + l16) * N_TOK + jn + kk * 32 + kcol);
                }
        }

        // S^T: D[m=j][n=i], A=K rows (prefetched), B=Q rows (LDS)
        f32x4 sacc[2][2];
#pragma unroll
        for (int a = 0; a < 2; a++)
#pragma unroll
            for (int b = 0; b < 2; b++) sacc[a][b] = (f32x4){0.f, 0.f, 0.f, 0.f};
#pragma unroll
        for (int kk = 0; kk < 2; kk++) {
            bf16x8 qf[2];
#pragma unroll
            for (int ib = 0; ib < 2; ib++)
                qf[ib] = *(const bf16x8*)(&Qs[wi * 32 + ib * 16 + l16][kk * 32 + kcol]);
#pragma unroll
            for (int jb = 0; jb < 2; jb++)
#pragma unroll
                for (int ib = 0; ib < 2; ib++)
                    sacc[jb][ib] = __builtin_amdgcn_mfma_f32_16x16x32_bf16(kc[jb][kk], qf[ib], sacc[jb][ib], 0, 0, 0);
        }

        // per-lane sparse-bias walk (+8.0 raw per hit; duplicates accumulate)
        const int jend = j0 + 64;
#pragma unroll
        for (int ib = 0; ib < 2; ib++) {
            int cu = curv[ib], pt = ptrv[ib];
            while (cu < jend) {
                int c = cu - j0;
                if ((c >> 5) == wq && ((c >> 2) & 3) == quad) {
                    int jb = (c >> 4) & 1, rr = c & 3;
                    float a0 = (rr == 0) ? 8.0f : 0.0f;
                    float a1 = (rr == 1) ? 8.0f : 0.0f;
                    float a2 = (rr == 2) ? 8.0f : 0.0f;
                    float a3 = (rr == 3) ? 8.0f : 0.0f;
                    if (jb == 0) {
                        sacc[0][ib][0] += a0; sacc[0][ib][1] += a1;
                        sacc[0][ib][2] += a2; sacc[0][ib][3] += a3;
                    } else {
                        sacc[1][ib][0] += a0; sacc[1][ib][1] += a1;
                        sacc[1][ib][2] += a2; sacc[1][ib][3] += a3;
                    }
                }
                pt++;
                cu = ssim[rowi[ib]][pt];
            }
            curv[ib] = cu; ptrv[ib] = pt;
        }

        // P = exp2(fma(s,C1,C2)) in-register; pack for b64 stores
        uint2 pk[2][2];
#pragma unroll
        for (int jb = 0; jb < 2; jb++)
#pragma unroll
            for (int ib = 0; ib < 2; ib++) {
                float e0 = exp2f(fmaf(sacc[jb][ib][0], C1, C2));
                float e1 = exp2f(fmaf(sacc[jb][ib][1], C1, C2));
                float e2 = exp2f(fmaf(sacc[jb][ib][2], C1, C2));
                float e3 = exp2f(fmaf(sacc[jb][ib][3], C1, C2));
                lsum[ib] += (e0 + e1) + (e2 + e3);
                pk[jb][ib].x = pack_bf2(e0, e1);
                pk[jb][ib].y = pack_bf2(e2, e3);
            }

        __syncthreads();   // prior tile's PV reads of P2 complete (WAR)
#pragma unroll
        for (int jb = 0; jb < 2; jb++)
#pragma unroll
            for (int ib = 0; ib < 2; ib++) {
                int i = wi * 32 + ib * 16 + l16;
                int cj = wq * 4 + jb * 2 + (quad >> 1);
                int phys = cj ^ (i & 7);
                *(uint2*)&P2[i * 64 + phys * 8 + (quad & 1) * 4] = pk[jb][ib];
            }
        __syncthreads();   // P2 visible

        // O = P.V: D[m=i][n=d], A=P2 rows (LDS b128), B=vT rows (prefetched)
#pragma unroll
        for (int kk = 0; kk < 2; kk++) {
            bf16x8 pf[2];
#pragma unroll
            for (int ib = 0; ib < 2; ib++) {
                int i = wi * 32 + ib * 16 + l16;
                int phys = (kk * 4 + quad) ^ (i & 7);
                pf[ib] = *(const bf16x8*)&P2[i * 64 + phys * 8];
            }
#pragma unroll
            for (int ib = 0; ib < 2; ib++)
#pragma unroll
                for (int db = 0; db < 2; db++)
                    Oacc[ib][db] = __builtin_amdgcn_mfma_f32_16x16x32_bf16(pf[ib], vc[db][kk], Oacc[ib][db], 0, 0, 0);
        }
    }

    // l: reduce over the 4 quads in-wave, combine the two wq halves via LDS
#pragma unroll
    for (int ib = 0; ib < 2; ib++) {
        float l = lsum[ib];
        l += __shfl_xor(l, 16, 64);
        l += __shfl_xor(l, 32, 64);
        if (quad == 0) psum[wq][wi * 32 + ib * 16 + l16] = l;
    }
    __syncthreads();
    if (tid < 64) linvLDS[tid] = 1.0f / (psum[0][tid] + psum[1][tid]);
    __syncthreads();

    // epilogue: scale, stage O tile into Qs ([i][d], stride 72), coalesced store
#pragma unroll
    for (int ib = 0; ib < 2; ib++)
#pragma unroll
        for (int db = 0; db < 2; db++)
#pragma unroll
            for (int r = 0; r < 4; r++) {
                int i = wi * 32 + ib * 16 + quad * 4 + r;
                int d = wq * 32 + db * 16 + l16;
                Qs[i][d] = f2bf(Oacc[ib][db][r] * linvLDS[i]);
            }
    __syncthreads();
#pragma unroll
    for (int p = 0; p < 2; p++) {
        int chunk = tid + p * 256, r = chunk >> 3, c8 = chunk & 7;
        *(bf16x8*)(Oout + (size_t)(qbase + r) * CDIM + hoff + c8 * 8) =
            *(const bf16x8*)(&Qs[r][c8 * 8]);
    }
}

extern "C" void kernel_launch(void* const* d_in, const int* in_sizes, int n_in,
                              void* d_out, int out_size, void* d_ws, size_t ws_size,
                              hipStream_t stream)
{
    const float* x   = (const float*)d_in[0];
    const int*   sim = (const int*)d_in[1];
    const float* Wq  = (const float*)d_in[2];
    const float* bq  = (const float*)d_in[3];
    const float* Wk  = (const float*)d_in[4];
    const float* bk  = (const float*)d_in[5];
    const float* Wv  = (const float*)d_in[6];
    const float* bv  = (const float*)d_in[7];
    const float* Wo  = (const float*)d_in[8];
    const float* bo  = (const float*)d_in[9];
    float* out = (float*)d_out;

    // ws layout (ushort units): xb(=ao) | q | k | vT | Wf | Wob | biasf(fp32)
    ushort_t* xb  = (ushort_t*)d_ws;
    ushort_t* q   = xb + SX;
    ushort_t* k   = q + SX;
    ushort_t* vT  = k + SX;
    ushort_t* Wf  = vT + SX;
    ushort_t* Wob = Wf + 3 * SW;
    float* biasf  = (float*)(Wob + SW);
    ushort_t* ao  = xb;   // xb dead after gemm_qkv128

    dim3 blk(256);
    {
        long total4 = (long)(SX + 4 * SW + 3 * CDIM) / 4;
        int nb = (int)((total4 + 255) / 256);
        convert_all<<<nb, blk, 0, stream>>>(x, Wq, Wk, Wv, Wo, bq, bk, bv,
                                            xb, Wf, Wob, biasf);
    }
    {
        dim3 g(N_TOK / 128, (3 * CDIM) / 128);
        gemm_qkv128<<<g, blk, 0, stream>>>(xb, Wf, biasf, q, k, vT);
    }
    {
        dim3 g(N_TOK / 64, NH);
        attn_kernel<<<g, blk, 0, stream>>>(q, k, vT, sim, ao);
    }
    {
        dim3 g(N_TOK / 128, CDIM / 64);
        gemm_out128<<<g, blk, 0, stream>>>(ao, Wob, bo, out);
    }
}

// Round 7
// 281.415 us; speedup vs baseline: 1.1779x; 1.1779x over previous
//
#include <hip/hip_runtime.h>
#include <hip/hip_bf16.h>
#include <stdint.h>

#define N_TOK 4096
#define CDIM 768
#define NH 12
#define HD 64
#define SX (N_TOK * CDIM)
#define SW (CDIM * CDIM)

typedef __attribute__((ext_vector_type(8))) short bf16x8;
typedef __attribute__((ext_vector_type(4))) float f32x4;
typedef unsigned short ushort_t;
typedef unsigned int uint_t;

typedef const __attribute__((address_space(1))) void* as1_cvp;
typedef __attribute__((address_space(3))) void* as3_vp;
#define GLD16(g, s) __builtin_amdgcn_global_load_lds((as1_cvp)(g), (as3_vp)(s), 16, 0, 0)

__device__ inline ushort_t f2bf(float f) {
    union { float f; uint_t u; } c; c.f = f;
    uint_t u = (c.u + 0x7FFFu + ((c.u >> 16) & 1u)) >> 16;
    return (ushort_t)u;
}
__device__ inline uint_t pack_bf2(float a, float b) {
    union { __hip_bfloat162 v; uint_t u; } c;
    c.v = __float22bfloat162_rn(make_float2(a, b));
    return c.u;
}

// fp32 -> bf16 one-shot conversion of x, Wq|Wk|Wv (concat), Wo; bq|bk|bv concat fp32.
__global__ __launch_bounds__(256) void convert_all(
    const float* __restrict__ x,
    const float* __restrict__ Wq, const float* __restrict__ Wk,
    const float* __restrict__ Wv, const float* __restrict__ Wo,
    const float* __restrict__ bq, const float* __restrict__ bk, const float* __restrict__ bv,
    ushort_t* __restrict__ xb, ushort_t* __restrict__ Wf,
    ushort_t* __restrict__ Wob, float* __restrict__ biasf)
{
    long i = ((long)blockIdx.x * 256 + threadIdx.x) * 4;
    const float* src; ushort_t* dst; long off;
    if (i < SX)               { src = x;  dst = xb;          off = i; }
    else if (i < SX + SW)     { src = Wq; dst = Wf;          off = i - SX; }
    else if (i < SX + 2*SW)   { src = Wk; dst = Wf + SW;     off = i - SX - SW; }
    else if (i < SX + 3*SW)   { src = Wv; dst = Wf + 2*SW;   off = i - SX - 2*SW; }
    else if (i < SX + 4*SW)   { src = Wo; dst = Wob;         off = i - SX - 3*SW; }
    else if (i < SX + 4*SW + 3*CDIM) {
        long b = i - (SX + 4*SW);
        const float* bs = (b < CDIM) ? bq + b : (b < 2*CDIM) ? bk + (b - CDIM) : bv + (b - 2*CDIM);
        *(float4*)(biasf + b) = *(const float4*)bs;
        return;
    } else return;
    float4 v4 = *(const float4*)(src + off);
    uint2 st = { pack_bf2(v4.x, v4.y), pack_bf2(v4.z, v4.w) };
    *(uint2*)(dst + off) = st;
}

// Fused QKV GEMM, m97-style: 128x128 tile, BK=64, global_load_lds(16B) into
// unpadded XOR-chunk-swizzled LDS. out[i][j] = sum_c xb[i][c]*Wf[j][c] + biasf[j].
// j<768 -> q, j<1536 -> k (row-major bf16); else v stored transposed vT[j][i].
__global__ __launch_bounds__(256) void gemm_qkv128(
    const ushort_t* __restrict__ xb, const ushort_t* __restrict__ Wf,
    const float* __restrict__ biasf,
    ushort_t* __restrict__ q, ushort_t* __restrict__ k, ushort_t* __restrict__ vT)
{
    __shared__ __align__(16) ushort_t Asm[128 * 64];
    __shared__ __align__(16) ushort_t Bsm[128 * 64];
    const int tid = threadIdx.x;
    const int w = tid >> 6, lane = tid & 63;
    const int quad = lane >> 4, l16 = lane & 15;
    const int row0 = blockIdx.x * 128;
    const int col0 = blockIdx.y * 128;
    const int rw = (w >> 1) * 64, cw = (w & 1) * 64;
    const int srow = lane >> 3;
    const int sc = ((lane & 7) ^ srow) * 8;
    const int swz = l16 & 7;

    f32x4 acc[4][4];
#pragma unroll
    for (int a = 0; a < 4; a++)
#pragma unroll
        for (int b = 0; b < 4; b++) acc[a][b] = (f32x4){0.f, 0.f, 0.f, 0.f};

    for (int kc = 0; kc < CDIM; kc += 64) {
        __syncthreads();
#pragma unroll
        for (int c = 0; c < 4; c++) {
            int ra = w * 32 + c * 8;
            GLD16(xb + (size_t)(row0 + ra + srow) * CDIM + kc + sc, &Asm[ra * 64]);
            GLD16(Wf + (size_t)(col0 + ra + srow) * CDIM + kc + sc, &Bsm[ra * 64]);
        }
        __syncthreads();
#pragma unroll
        for (int kk = 0; kk < 2; kk++) {
            const int po = ((kk * 4 + quad) ^ swz) * 8;
            bf16x8 af[4], bfr[4];
#pragma unroll
            for (int rb = 0; rb < 4; rb++)
                af[rb] = *(const bf16x8*)&Asm[(rw + rb * 16 + l16) * 64 + po];
#pragma unroll
            for (int cb = 0; cb < 4; cb++)
                bfr[cb] = *(const bf16x8*)&Bsm[(cw + cb * 16 + l16) * 64 + po];
#pragma unroll
            for (int rb = 0; rb < 4; rb++)
#pragma unroll
                for (int cb = 0; cb < 4; cb++)
                    acc[rb][cb] = __builtin_amdgcn_mfma_f32_16x16x32_bf16(af[rb], bfr[cb], acc[rb][cb], 0, 0, 0);
        }
    }

    if (col0 < 2 * CDIM) {
        ushort_t* dst = (col0 < CDIM) ? q : k;
        const int jb0 = (col0 < CDIM) ? col0 : col0 - CDIM;
#pragma unroll
        for (int cb = 0; cb < 4; cb++) {
            int jg = cw + cb * 16 + l16;
            float bv_ = biasf[col0 + jg];
#pragma unroll
            for (int rb = 0; rb < 4; rb++)
#pragma unroll
                for (int r = 0; r < 4; r++) {
                    int i = row0 + rw + rb * 16 + quad * 4 + r;
                    dst[(size_t)i * CDIM + jb0 + jg] = f2bf(acc[rb][cb][r] + bv_);
                }
        }
    } else {
        const int jv0 = col0 - 2 * CDIM;
        ushort_t* T = Asm;
#pragma unroll
        for (int h = 0; h < 2; h++) {
            __syncthreads();
            if ((w & 1) == h) {
#pragma unroll
                for (int cb = 0; cb < 4; cb++) {
                    int jl = cb * 16 + l16;
                    float bv_ = biasf[col0 + h * 64 + jl];
#pragma unroll
                    for (int rb = 0; rb < 4; rb++)
#pragma unroll
                        for (int r = 0; r < 4; r++) {
                            int i = rw + rb * 16 + quad * 4 + r;
                            int cch = i >> 3, w8 = i & 7;
                            T[jl * 128 + ((cch ^ (jl & 7)) * 8) + w8] =
                                f2bf(acc[rb][cb][r] + bv_);
                        }
                }
            }
            __syncthreads();
#pragma unroll
            for (int p = 0; p < 4; p++) {
                int t = tid + p * 256, jl = t >> 4, i8 = t & 15;
                *(bf16x8*)(vT + (size_t)(jv0 + h * 64 + jl) * N_TOK + row0 + i8 * 8) =
                    *(const bf16x8*)&T[jl * 128 + ((i8 ^ (jl & 7)) * 8)];
            }
        }
    }
}

// Output projection: 128x64 tile, same m97 staging. fp32 out.
__global__ __launch_bounds__(256) void gemm_out128(
    const ushort_t* __restrict__ A, const ushort_t* __restrict__ W,
    const float* __restrict__ bias, float* __restrict__ out)
{
    __shared__ __align__(16) ushort_t Asm[128 * 64];
    __shared__ __align__(16) ushort_t Bsm[64 * 64];
    const int tid = threadIdx.x;
    const int w = tid >> 6, lane = tid & 63;
    const int quad = lane >> 4, l16 = lane & 15;
    const int row0 = blockIdx.x * 128;
    const int col0 = blockIdx.y * 64;
    const int rw = (w >> 1) * 64, cw = (w & 1) * 32;
    const int srow = lane >> 3;
    const int sc = ((lane & 7) ^ srow) * 8;
    const int swz = l16 & 7;

    f32x4 acc[4][2];
#pragma unroll
    for (int a = 0; a < 4; a++)
#pragma unroll
        for (int b = 0; b < 2; b++) acc[a][b] = (f32x4){0.f, 0.f, 0.f, 0.f};

    for (int kc = 0; kc < CDIM; kc += 64) {
        __syncthreads();
#pragma unroll
        for (int c = 0; c < 4; c++) {
            int ra = w * 32 + c * 8;
            GLD16(A + (size_t)(row0 + ra + srow) * CDIM + kc + sc, &Asm[ra * 64]);
        }
#pragma unroll
        for (int c = 0; c < 2; c++) {
            int rb_ = w * 16 + c * 8;
            GLD16(W + (size_t)(col0 + rb_ + srow) * CDIM + kc + sc, &Bsm[rb_ * 64]);
        }
        __syncthreads();
#pragma unroll
        for (int kk = 0; kk < 2; kk++) {
            const int po = ((kk * 4 + quad) ^ swz) * 8;
            bf16x8 af[4], bfr[2];
#pragma unroll
            for (int rb = 0; rb < 4; rb++)
                af[rb] = *(const bf16x8*)&Asm[(rw + rb * 16 + l16) * 64 + po];
#pragma unroll
            for (int cb = 0; cb < 2; cb++)
                bfr[cb] = *(const bf16x8*)&Bsm[(cw + cb * 16 + l16) * 64 + po];
#pragma unroll
            for (int rb = 0; rb < 4; rb++)
#pragma unroll
                for (int cb = 0; cb < 2; cb++)
                    acc[rb][cb] = __builtin_amdgcn_mfma_f32_16x16x32_bf16(af[rb], bfr[cb], acc[rb][cb], 0, 0, 0);
        }
    }
#pragma unroll
    for (int cb = 0; cb < 2; cb++) {
        int j = col0 + cw + cb * 16 + l16;
        float bv_ = bias[j];
#pragma unroll
        for (int rb = 0; rb < 4; rb++)
#pragma unroll
            for (int r = 0; r < 4; r++) {
                int i = row0 + rw + rb * 16 + quad * 4 + r;
                out[(size_t)i * CDIM + j] = acc[rb][cb][r] + bv_;
            }
    }
}

// Flash attention v3: S^T = K.Q^T with K, vT staged in DOUBLE-BUFFERED LDS via
// global_load_lds (prefetch issued one tile ahead; QK+softmax hides latency).
// Q fragments hoisted to registers once. Static-max softmax in-register;
// P: 4xb64 swizzled write -> 4xb128 read. 2 barriers per tile.
__global__ __launch_bounds__(256, 3) void attn_kernel(
    const ushort_t* __restrict__ Q, const ushort_t* __restrict__ K,
    const ushort_t* __restrict__ VT, const int* __restrict__ sim,
    ushort_t* __restrict__ Oout)
{
    __shared__ __align__(16) ushort_t Qsw[64 * 64];     // swizzled; reused as O tile
    __shared__ __align__(16) ushort_t Ks[2][64 * 64];   // rows j, swizzled
    __shared__ __align__(16) ushort_t Vts[2][64 * 64];  // rows d, swizzled
    __shared__ __align__(16) ushort_t P2[64 * 64];      // rows i, swizzled
    __shared__ int ssim[64][12];
    __shared__ float psum[2][64];
    __shared__ float linvLDS[64];

    const int tid = threadIdx.x;
    const int wave = tid >> 6, lane = tid & 63;
    const int quad = lane >> 4, l16 = lane & 15;
    const int wq = wave >> 1;    // j-half / d-half
    const int wi = wave & 1;     // i-half
    const int qbase = blockIdx.x * 64;
    const int hoff = blockIdx.y * HD;

    const float C1 = 0.18033688011112042f;   // 0.125 * log2(e)
    const float C2 = -11.541560327111707f;   // -8 * log2(e)

    const int srow = lane >> 3;
    const int sc = ((lane & 7) ^ srow) * 8;  // swizzled source chunk

    // prologue: stage Q + tile-0 K/vT (async), sort bias lists
#pragma unroll
    for (int c = 0; c < 2; c++) {
        int ra = wave * 16 + c * 8;
        GLD16(Q + (size_t)(qbase + ra + srow) * CDIM + hoff + sc, &Qsw[ra * 64]);
        GLD16(K + (size_t)(ra + srow) * CDIM + hoff + sc, &Ks[0][ra * 64]);
        GLD16(VT + (size_t)(hoff + ra + srow) * N_TOK + sc, &Vts[0][ra * 64]);
    }
    if (tid < 64) {
        int vb_[10];
        const int* sp = sim + (size_t)(qbase + tid) * 10;
#pragma unroll
        for (int e = 0; e < 10; e++) vb_[e] = sp[e];
#pragma unroll
        for (int round = 0; round < 10; round++)
#pragma unroll
            for (int i = (round & 1); i + 1 < 10; i += 2) {
                int a = vb_[i], b = vb_[i + 1];
                vb_[i] = min(a, b); vb_[i + 1] = max(a, b);
            }
#pragma unroll
        for (int e = 0; e < 10; e++) ssim[tid][e] = vb_[e];
        ssim[tid][10] = 0x7FFFFFFF;
        ssim[tid][11] = 0x7FFFFFFF;
    }
    __syncthreads();   // staging + ssim visible

    // hoist Q fragments (tile-invariant)
    bf16x8 qf[2][2];
#pragma unroll
    for (int ib = 0; ib < 2; ib++)
#pragma unroll
        for (int kk = 0; kk < 2; kk++) {
            int i = wi * 32 + ib * 16 + l16;
            int phys = (kk * 4 + quad) ^ (i & 7);
            qf[ib][kk] = *(const bf16x8*)&Qsw[i * 64 + phys * 8];
        }

    const int rowi[2] = { wi * 32 + l16, wi * 32 + 16 + l16 };
    int curv[2], ptrv[2];
    float lsum[2] = { 0.f, 0.f };
#pragma unroll
    for (int ib = 0; ib < 2; ib++) { ptrv[ib] = 0; curv[ib] = ssim[rowi[ib]][0]; }

    f32x4 Oacc[2][2];
#pragma unroll
    for (int a = 0; a < 2; a++)
#pragma unroll
        for (int b = 0; b < 2; b++) Oacc[a][b] = (f32x4){0.f, 0.f, 0.f, 0.f};

    for (int t = 0; t < N_TOK / 64; t++) {
        const int cur = t & 1;
        const int j0 = t * 64;
        if (t) __syncthreads();   // B0: prior tile's PV reads (P2, Vts, Ks) done

        if (t + 1 < N_TOK / 64) {  // prefetch next tile into other buffer
            const int jn = j0 + 64, nb = 1 - cur;
#pragma unroll
            for (int c = 0; c < 2; c++) {
                int ra = wave * 16 + c * 8;
                GLD16(K + (size_t)(jn + ra + srow) * CDIM + hoff + sc, &Ks[nb][ra * 64]);
                GLD16(VT + (size_t)(hoff + ra + srow) * N_TOK + jn + sc, &Vts[nb][ra * 64]);
            }
        }

        // S^T = K.Q^T : D[m=j][n=i]
        f32x4 sacc[2][2];
#pragma unroll
        for (int a = 0; a < 2; a++)
#pragma unroll
            for (int b = 0; b < 2; b++) sacc[a][b] = (f32x4){0.f, 0.f, 0.f, 0.f};
#pragma unroll
        for (int kk = 0; kk < 2; kk++) {
            bf16x8 ka[2];
#pragma unroll
            for (int jb = 0; jb < 2; jb++) {
                int j = wq * 32 + jb * 16 + l16;
                int phys = (kk * 4 + quad) ^ (j & 7);
                ka[jb] = *(const bf16x8*)&Ks[cur][j * 64 + phys * 8];
            }
#pragma unroll
            for (int jb = 0; jb < 2; jb++)
#pragma unroll
                for (int ib = 0; ib < 2; ib++)
                    sacc[jb][ib] = __builtin_amdgcn_mfma_f32_16x16x32_bf16(ka[jb], qf[ib][kk], sacc[jb][ib], 0, 0, 0);
        }

        // per-lane sparse-bias walk (+8.0 raw per hit; duplicates accumulate)
        const int jend = j0 + 64;
#pragma unroll
        for (int ib = 0; ib < 2; ib++) {
            int cu = curv[ib], pt = ptrv[ib];
            while (cu < jend) {
                int c = cu - j0;
                if ((c >> 5) == wq && ((c >> 2) & 3) == quad) {
                    int jb = (c >> 4) & 1, rr = c & 3;
                    float a0 = (rr == 0) ? 8.0f : 0.0f;
                    float a1 = (rr == 1) ? 8.0f : 0.0f;
                    float a2 = (rr == 2) ? 8.0f : 0.0f;
                    float a3 = (rr == 3) ? 8.0f : 0.0f;
                    if (jb == 0) {
                        sacc[0][ib][0] += a0; sacc[0][ib][1] += a1;
                        sacc[0][ib][2] += a2; sacc[0][ib][3] += a3;
                    } else {
                        sacc[1][ib][0] += a0; sacc[1][ib][1] += a1;
                        sacc[1][ib][2] += a2; sacc[1][ib][3] += a3;
                    }
                }
                pt++;
                cu = ssim[rowi[ib]][pt];
            }
            curv[ib] = cu; ptrv[ib] = pt;
        }

        // P = exp2(fma(s,C1,C2)); pack; write P2 (WAR safe: B0 covered it)
#pragma unroll
        for (int jb = 0; jb < 2; jb++)
#pragma unroll
            for (int ib = 0; ib < 2; ib++) {
                float e0 = exp2f(fmaf(sacc[jb][ib][0], C1, C2));
                float e1 = exp2f(fmaf(sacc[jb][ib][1], C1, C2));
                float e2 = exp2f(fmaf(sacc[jb][ib][2], C1, C2));
                float e3 = exp2f(fmaf(sacc[jb][ib][3], C1, C2));
                lsum[ib] += (e0 + e1) + (e2 + e3);
                uint2 pk = { pack_bf2(e0, e1), pack_bf2(e2, e3) };
                int i = wi * 32 + ib * 16 + l16;
                int cj = wq * 4 + jb * 2 + (quad >> 1);
                int phys = cj ^ (i & 7);
                *(uint2*)&P2[i * 64 + phys * 8 + (quad & 1) * 4] = pk;
            }
        __syncthreads();   // B1: P2 visible; prefetch drained (vmcnt) + published

        // O = P.V : D[m=i][n=d]
#pragma unroll
        for (int kk = 0; kk < 2; kk++) {
            bf16x8 pf[2], vf[2];
#pragma unroll
            for (int ib = 0; ib < 2; ib++) {
                int i = wi * 32 + ib * 16 + l16;
                int phys = (kk * 4 + quad) ^ (i & 7);
                pf[ib] = *(const bf16x8*)&P2[i * 64 + phys * 8];
            }
#pragma unroll
            for (int db = 0; db < 2; db++) {
                int d = wq * 32 + db * 16 + l16;
                int phys = (kk * 4 + quad) ^ (d & 7);
                vf[db] = *(const bf16x8*)&Vts[cur][d * 64 + phys * 8];
            }
#pragma unroll
            for (int ib = 0; ib < 2; ib++)
#pragma unroll
                for (int db = 0; db < 2; db++)
                    Oacc[ib][db] = __builtin_amdgcn_mfma_f32_16x16x32_bf16(pf[ib], vf[db], Oacc[ib][db], 0, 0, 0);
        }
    }

    // l: reduce over quads in-wave, combine wq halves via LDS
#pragma unroll
    for (int ib = 0; ib < 2; ib++) {
        float l = lsum[ib];
        l += __shfl_xor(l, 16, 64);
        l += __shfl_xor(l, 32, 64);
        if (quad == 0) psum[wq][wi * 32 + ib * 16 + l16] = l;
    }
    __syncthreads();
    if (tid < 64) linvLDS[tid] = 1.0f / (psum[0][tid] + psum[1][tid]);
    __syncthreads();

    // epilogue: scale, stage O tile into Qsw (swizzled), coalesced store
#pragma unroll
    for (int ib = 0; ib < 2; ib++)
#pragma unroll
        for (int db = 0; db < 2; db++)
#pragma unroll
            for (int r = 0; r < 4; r++) {
                int i = wi * 32 + ib * 16 + quad * 4 + r;
                int d = wq * 32 + db * 16 + l16;
                Qsw[i * 64 + (((d >> 3) ^ (i & 7)) * 8) + (d & 7)] =
                    f2bf(Oacc[ib][db][r] * linvLDS[i]);
            }
    __syncthreads();
#pragma unroll
    for (int p = 0; p < 2; p++) {
        int chunk = tid + p * 256, r = chunk >> 3, c8 = chunk & 7;
        *(bf16x8*)(Oout + (size_t)(qbase + r) * CDIM + hoff + c8 * 8) =
            *(const bf16x8*)&Qsw[r * 64 + ((c8 ^ (r & 7)) * 8)];
    }
}

extern "C" void kernel_launch(void* const* d_in, const int* in_sizes, int n_in,
                              void* d_out, int out_size, void* d_ws, size_t ws_size,
                              hipStream_t stream)
{
    const float* x   = (const float*)d_in[0];
    const int*   sim = (const int*)d_in[1];
    const float* Wq  = (const float*)d_in[2];
    const float* bq  = (const float*)d_in[3];
    const float* Wk  = (const float*)d_in[4];
    const float* bk  = (const float*)d_in[5];
    const float* Wv  = (const float*)d_in[6];
    const float* bv  = (const float*)d_in[7];
    const float* Wo  = (const float*)d_in[8];
    const float* bo  = (const float*)d_in[9];
    float* out = (float*)d_out;

    // ws layout (ushort units): xb(=ao) | q | k | vT | Wf | Wob | biasf(fp32)
    ushort_t* xb  = (ushort_t*)d_ws;
    ushort_t* q   = xb + SX;
    ushort_t* k   = q + SX;
    ushort_t* vT  = k + SX;
    ushort_t* Wf  = vT + SX;
    ushort_t* Wob = Wf + 3 * SW;
    float* biasf  = (float*)(Wob + SW);
    ushort_t* ao  = xb;   // xb dead after gemm_qkv128

    dim3 blk(256);
    {
        long total4 = (long)(SX + 4 * SW + 3 * CDIM) / 4;
        int nb = (int)((total4 + 255) / 256);
        convert_all<<<nb, blk, 0, stream>>>(x, Wq, Wk, Wv, Wo, bq, bk, bv,
                                            xb, Wf, Wob, biasf);
    }
    {
        dim3 g(N_TOK / 128, (3 * CDIM) / 128);
        gemm_qkv128<<<g, blk, 0, stream>>>(xb, Wf, biasf, q, k, vT);
    }
    {
        dim3 g(N_TOK / 64, NH);
        attn_kernel<<<g, blk, 0, stream>>>(q, k, vT, sim, ao);
    }
    {
        dim3 g(N_TOK / 128, CDIM / 64);
        gemm_out128<<<g, blk, 0, stream>>>(ao, Wob, bo, out);
    }
}

// Round 8
// 251.841 us; speedup vs baseline: 1.3162x; 1.1174x over previous
//
#include <hip/hip_runtime.h>
#include <hip/hip_bf16.h>
#include <stdint.h>

#define N_TOK 4096
#define CDIM 768
#define NH 12
#define HD 64
#define SX (N_TOK * CDIM)
#define SW (CDIM * CDIM)

typedef __attribute__((ext_vector_type(8))) short bf16x8;
typedef __attribute__((ext_vector_type(4))) float f32x4;
typedef unsigned short ushort_t;
typedef unsigned int uint_t;

typedef const __attribute__((address_space(1))) void* as1_cvp;
typedef __attribute__((address_space(3))) void* as3_vp;
#define GLD16(g, s) __builtin_amdgcn_global_load_lds((as1_cvp)(g), (as3_vp)(s), 16, 0, 0)

__device__ inline ushort_t f2bf(float f) {
    union { float f; uint_t u; } c; c.f = f;
    uint_t u = (c.u + 0x7FFFu + ((c.u >> 16) & 1u)) >> 16;
    return (ushort_t)u;
}
__device__ inline uint_t pack_bf2(float a, float b) {
    union { __hip_bfloat162 v; uint_t u; } c;
    c.v = __float22bfloat162_rn(make_float2(a, b));
    return c.u;
}

// fp32 -> bf16 one-shot conversion of x, Wq|Wk|Wv (concat), Wo; bq|bk|bv concat fp32.
__global__ __launch_bounds__(256) void convert_all(
    const float* __restrict__ x,
    const float* __restrict__ Wq, const float* __restrict__ Wk,
    const float* __restrict__ Wv, const float* __restrict__ Wo,
    const float* __restrict__ bq, const float* __restrict__ bk, const float* __restrict__ bv,
    ushort_t* __restrict__ xb, ushort_t* __restrict__ Wf,
    ushort_t* __restrict__ Wob, float* __restrict__ biasf)
{
    long i = ((long)blockIdx.x * 256 + threadIdx.x) * 4;
    const float* src; ushort_t* dst; long off;
    if (i < SX)               { src = x;  dst = xb;          off = i; }
    else if (i < SX + SW)     { src = Wq; dst = Wf;          off = i - SX; }
    else if (i < SX + 2*SW)   { src = Wk; dst = Wf + SW;     off = i - SX - SW; }
    else if (i < SX + 3*SW)   { src = Wv; dst = Wf + 2*SW;   off = i - SX - 2*SW; }
    else if (i < SX + 4*SW)   { src = Wo; dst = Wob;         off = i - SX - 3*SW; }
    else if (i < SX + 4*SW + 3*CDIM) {
        long b = i - (SX + 4*SW);
        const float* bs = (b < CDIM) ? bq + b : (b < 2*CDIM) ? bk + (b - CDIM) : bv + (b - 2*CDIM);
        *(float4*)(biasf + b) = *(const float4*)bs;
        return;
    } else return;
    float4 v4 = *(const float4*)(src + off);
    uint2 st = { pack_bf2(v4.x, v4.y), pack_bf2(v4.z, v4.w) };
    *(uint2*)(dst + off) = st;
}

// Fused QKV GEMM: 128x64 tiles (1152 blocks), BK=64, GLD16 staging, XOR-swizzled LDS.
// out[i][j] = sum_c xb[i][c]*Wf[j][c] + biasf[j]. j<768 -> q (PRE-SCALED by C1 for
// softmax exp2 folding); j<1536 -> k; else v stored transposed vT[j][i].
__global__ __launch_bounds__(256) void gemm_qkv(
    const ushort_t* __restrict__ xb, const ushort_t* __restrict__ Wf,
    const float* __restrict__ biasf,
    ushort_t* __restrict__ q, ushort_t* __restrict__ k, ushort_t* __restrict__ vT)
{
    __shared__ __align__(16) ushort_t Asm[128 * 64];
    __shared__ __align__(16) ushort_t Bsm[64 * 64];
    const int tid = threadIdx.x;
    const int w = tid >> 6, lane = tid & 63;
    const int quad = lane >> 4, l16 = lane & 15;
    const int row0 = blockIdx.x * 128;
    const int col0 = blockIdx.y * 64;
    const int rw = w * 32;
    const int srow = lane >> 3;
    const int sc = ((lane & 7) ^ srow) * 8;
    const int swz = l16 & 7;
    const float C1 = 0.18033688011112042f;   // 0.125 * log2(e)

    f32x4 acc[2][4];
#pragma unroll
    for (int a = 0; a < 2; a++)
#pragma unroll
        for (int b = 0; b < 4; b++) acc[a][b] = (f32x4){0.f, 0.f, 0.f, 0.f};

    for (int kc = 0; kc < CDIM; kc += 64) {
        __syncthreads();
#pragma unroll
        for (int c = 0; c < 4; c++) {
            int ra = w * 32 + c * 8;
            GLD16(xb + (size_t)(row0 + ra + srow) * CDIM + kc + sc, &Asm[ra * 64]);
        }
#pragma unroll
        for (int c = 0; c < 2; c++) {
            int rb_ = w * 16 + c * 8;
            GLD16(Wf + (size_t)(col0 + rb_ + srow) * CDIM + kc + sc, &Bsm[rb_ * 64]);
        }
        __syncthreads();
#pragma unroll
        for (int kk = 0; kk < 2; kk++) {
            const int po = ((kk * 4 + quad) ^ swz) * 8;
            bf16x8 af[2], bfr[4];
#pragma unroll
            for (int rb = 0; rb < 2; rb++)
                af[rb] = *(const bf16x8*)&Asm[(rw + rb * 16 + l16) * 64 + po];
#pragma unroll
            for (int cb = 0; cb < 4; cb++)
                bfr[cb] = *(const bf16x8*)&Bsm[(cb * 16 + l16) * 64 + po];
#pragma unroll
            for (int rb = 0; rb < 2; rb++)
#pragma unroll
                for (int cb = 0; cb < 4; cb++)
                    acc[rb][cb] = __builtin_amdgcn_mfma_f32_16x16x32_bf16(af[rb], bfr[cb], acc[rb][cb], 0, 0, 0);
        }
    }

    if (col0 < 2 * CDIM) {
        const bool isQ = (col0 < CDIM);
        ushort_t* dst = isQ ? q : k;
        const int jb0 = isQ ? col0 : col0 - CDIM;
        const float scale = isQ ? C1 : 1.0f;
#pragma unroll
        for (int cb = 0; cb < 4; cb++) {
            int j = jb0 + cb * 16 + l16;
            float bv_ = biasf[col0 + cb * 16 + l16];
#pragma unroll
            for (int rb = 0; rb < 2; rb++)
#pragma unroll
                for (int r = 0; r < 4; r++) {
                    int i = row0 + rw + rb * 16 + quad * 4 + r;
                    dst[(size_t)i * CDIM + j] = f2bf((acc[rb][cb][r] + bv_) * scale);
                }
        }
    } else {
        // vT: 64j x 128i transpose through Asm (swizzled), coalesced stores
        const int jv0 = col0 - 2 * CDIM;
        ushort_t* T = Asm;
        __syncthreads();
#pragma unroll
        for (int cb = 0; cb < 4; cb++) {
            int jl = cb * 16 + l16;
            float bv_ = biasf[col0 + jl];
#pragma unroll
            for (int rb = 0; rb < 2; rb++)
#pragma unroll
                for (int r = 0; r < 4; r++) {
                    int i = rw + rb * 16 + quad * 4 + r;
                    T[jl * 128 + (((i >> 3) ^ (jl & 7)) * 8) + (i & 7)] =
                        f2bf(acc[rb][cb][r] + bv_);
                }
        }
        __syncthreads();
#pragma unroll
        for (int p = 0; p < 4; p++) {
            int t = tid + p * 256, jl = t >> 4, i8 = t & 15;
            *(bf16x8*)(vT + (size_t)(jv0 + jl) * N_TOK + row0 + i8 * 8) =
                *(const bf16x8*)&T[jl * 128 + ((i8 ^ (jl & 7)) * 8)];
        }
    }
}

// Output projection: 64x64 tiles (768 blocks = 3/CU balanced). fp32 out.
__global__ __launch_bounds__(256) void gemm_out(
    const ushort_t* __restrict__ A, const ushort_t* __restrict__ W,
    const float* __restrict__ bias, float* __restrict__ out)
{
    __shared__ __align__(16) ushort_t Asm[64 * 64];
    __shared__ __align__(16) ushort_t Bsm[64 * 64];
    const int tid = threadIdx.x;
    const int w = tid >> 6, lane = tid & 63;
    const int quad = lane >> 4, l16 = lane & 15;
    const int row0 = blockIdx.x * 64;
    const int col0 = blockIdx.y * 64;
    const int srow = lane >> 3;
    const int sc = ((lane & 7) ^ srow) * 8;
    const int swz = l16 & 7;

    f32x4 acc[4];
#pragma unroll
    for (int b = 0; b < 4; b++) acc[b] = (f32x4){0.f, 0.f, 0.f, 0.f};

    for (int kc = 0; kc < CDIM; kc += 64) {
        __syncthreads();
#pragma unroll
        for (int c = 0; c < 2; c++) {
            int ra = w * 16 + c * 8;
            GLD16(A + (size_t)(row0 + ra + srow) * CDIM + kc + sc, &Asm[ra * 64]);
            GLD16(W + (size_t)(col0 + ra + srow) * CDIM + kc + sc, &Bsm[ra * 64]);
        }
        __syncthreads();
#pragma unroll
        for (int kk = 0; kk < 2; kk++) {
            const int po = ((kk * 4 + quad) ^ swz) * 8;
            bf16x8 af = *(const bf16x8*)&Asm[(w * 16 + l16) * 64 + po];
#pragma unroll
            for (int cb = 0; cb < 4; cb++) {
                bf16x8 bfr = *(const bf16x8*)&Bsm[(cb * 16 + l16) * 64 + po];
                acc[cb] = __builtin_amdgcn_mfma_f32_16x16x32_bf16(af, bfr, acc[cb], 0, 0, 0);
            }
        }
    }
#pragma unroll
    for (int cb = 0; cb < 4; cb++) {
        int j = col0 + cb * 16 + l16;
        float bv_ = bias[j];
#pragma unroll
        for (int r = 0; r < 4; r++) {
            int i = row0 + w * 16 + quad * 4 + r;
            out[(size_t)i * CDIM + j] = acc[cb][r] + bv_;
        }
    }
}

// Flash attention v4: 32 q-rows per block -> 1536 blocks = 6/CU (occupancy play).
// S^T = K.Q'^T with q pre-scaled by C1; P = exp2(s') directly (shift-invariance:
// no max subtraction needed, exponents bounded ~23 << 128). Bias hit = +log2(e).
// Single-buffered K/vT staging via GLD16 (22 KB LDS), Q frags per-lane from global,
// P via 2xb64 swizzled write -> b128 read. 3 barriers/tile; 6-block interleave
// hides DMA latency (m114 wave-level overlap).
__global__ __launch_bounds__(256, 6) void attn_kernel(
    const ushort_t* __restrict__ Q, const ushort_t* __restrict__ K,
    const ushort_t* __restrict__ VT, const int* __restrict__ sim,
    ushort_t* __restrict__ Oout)
{
    __shared__ __align__(16) ushort_t Ks[64 * 64];   // j rows; reused as O tile
    __shared__ __align__(16) ushort_t Vts[64 * 64];  // d rows
    __shared__ __align__(16) ushort_t P2[32 * 64];   // i rows, swizzled
    __shared__ int ssim[32][12];
    __shared__ float psum[4][32];
    __shared__ float linvLDS[32];

    const int tid = threadIdx.x;
    const int wave = tid >> 6, lane = tid & 63;
    const int quad = lane >> 4, l16 = lane & 15;
    const int qbase = blockIdx.x * 32;
    const int hoff = blockIdx.y * HD;
    const float LOG2E = 1.4426950408889634f;

    const int srow = lane >> 3;
    const int sc = ((lane & 7) ^ srow) * 8;
    const int swz = l16 & 7;

    // Q fragments per-lane from global (tile-invariant B-operands)
    bf16x8 qf[2][2];
#pragma unroll
    for (int ib = 0; ib < 2; ib++)
#pragma unroll
        for (int kk = 0; kk < 2; kk++)
            qf[ib][kk] = *(const bf16x8*)(Q + (size_t)(qbase + ib * 16 + l16) * CDIM
                                          + hoff + kk * 32 + quad * 8);

    // sorted per-row bias indices (32 rows)
    if (tid < 32) {
        int vb_[10];
        const int* sp = sim + (size_t)(qbase + tid) * 10;
#pragma unroll
        for (int e = 0; e < 10; e++) vb_[e] = sp[e];
#pragma unroll
        for (int round = 0; round < 10; round++)
#pragma unroll
            for (int i = (round & 1); i + 1 < 10; i += 2) {
                int a = vb_[i], b = vb_[i + 1];
                vb_[i] = min(a, b); vb_[i + 1] = max(a, b);
            }
#pragma unroll
        for (int e = 0; e < 10; e++) ssim[tid][e] = vb_[e];
        ssim[tid][10] = 0x7FFFFFFF;
        ssim[tid][11] = 0x7FFFFFFF;
    }
    __syncthreads();

    int curv[2], ptrv[2];
    float lsum[2] = { 0.f, 0.f };
#pragma unroll
    for (int ib = 0; ib < 2; ib++) {
        ptrv[ib] = 0;
        curv[ib] = ssim[ib * 16 + l16][0];
    }
    f32x4 Oacc[2];
#pragma unroll
    for (int a = 0; a < 2; a++) Oacc[a] = (f32x4){0.f, 0.f, 0.f, 0.f};

    for (int j0 = 0; j0 < N_TOK; j0 += 64) {
        __syncthreads();   // B0: prior tile's Ks/Vts/P2 reads complete (WAR)
#pragma unroll
        for (int c = 0; c < 2; c++) {
            int ra = wave * 16 + c * 8;
            GLD16(K + (size_t)(j0 + ra + srow) * CDIM + hoff + sc, &Ks[ra * 64]);
            GLD16(VT + (size_t)(hoff + ra + srow) * N_TOK + j0 + sc, &Vts[ra * 64]);
        }
        __syncthreads();   // B1: staging visible

        // S^T = K.Q'^T : D[m=j16 (this wave)][n=i32]
        f32x4 sacc[2];
#pragma unroll
        for (int a = 0; a < 2; a++) sacc[a] = (f32x4){0.f, 0.f, 0.f, 0.f};
#pragma unroll
        for (int kk = 0; kk < 2; kk++) {
            bf16x8 ka = *(const bf16x8*)&Ks[(wave * 16 + l16) * 64 + (((kk * 4 + quad) ^ swz) * 8)];
#pragma unroll
            for (int ib = 0; ib < 2; ib++)
                sacc[ib] = __builtin_amdgcn_mfma_f32_16x16x32_bf16(ka, qf[ib][kk], sacc[ib], 0, 0, 0);
        }

        // per-lane sparse-bias walk: +log2(e) per hit (duplicates accumulate)
        const int jend = j0 + 64;
#pragma unroll
        for (int ib = 0; ib < 2; ib++) {
            int cu = curv[ib], pt = ptrv[ib];
            while (cu < jend) {
                int c = cu - j0;
                if ((c >> 4) == wave && ((c >> 2) & 3) == quad) {
                    int rr = c & 3;
                    sacc[ib][0] += (rr == 0) ? LOG2E : 0.f;
                    sacc[ib][1] += (rr == 1) ? LOG2E : 0.f;
                    sacc[ib][2] += (rr == 2) ? LOG2E : 0.f;
                    sacc[ib][3] += (rr == 3) ? LOG2E : 0.f;
                }
                pt++;
                cu = ssim[ib * 16 + l16][pt];
            }
            curv[ib] = cu; ptrv[ib] = pt;
        }

        // P = exp2(s') directly; pack; swizzled b64 store into P2
#pragma unroll
        for (int ib = 0; ib < 2; ib++) {
            float e0 = exp2f(sacc[ib][0]);
            float e1 = exp2f(sacc[ib][1]);
            float e2 = exp2f(sacc[ib][2]);
            float e3 = exp2f(sacc[ib][3]);
            lsum[ib] += (e0 + e1) + (e2 + e3);
            uint2 pk = { pack_bf2(e0, e1), pack_bf2(e2, e3) };
            int i = ib * 16 + l16;
            int cj = wave * 2 + (quad >> 1);
            int phys = cj ^ (i & 7);
            *(uint2*)&P2[i * 64 + phys * 8 + (quad & 1) * 4] = pk;
        }
        __syncthreads();   // B2: P2 visible

        // O = P.V : D[m=i32][n=d16 (this wave)]
#pragma unroll
        for (int kk = 0; kk < 2; kk++) {
            bf16x8 vf = *(const bf16x8*)&Vts[(wave * 16 + l16) * 64 + (((kk * 4 + quad) ^ swz) * 8)];
#pragma unroll
            for (int ib = 0; ib < 2; ib++) {
                int i = ib * 16 + l16;
                bf16x8 pf = *(const bf16x8*)&P2[i * 64 + (((kk * 4 + quad) ^ (i & 7)) * 8)];
                Oacc[ib] = __builtin_amdgcn_mfma_f32_16x16x32_bf16(pf, vf, Oacc[ib], 0, 0, 0);
            }
        }
    }

    // l: quad-reduce in-wave, combine 4 waves (j-slices) via LDS
#pragma unroll
    for (int ib = 0; ib < 2; ib++) {
        float l = lsum[ib];
        l += __shfl_xor(l, 16, 64);
        l += __shfl_xor(l, 32, 64);
        if (quad == 0) psum[wave][ib * 16 + l16] = l;
    }
    __syncthreads();
    if (tid < 32)
        linvLDS[tid] = 1.0f / (psum[0][tid] + psum[1][tid] + psum[2][tid] + psum[3][tid]);
    __syncthreads();

    // epilogue: scale, stage O tile into Ks as [32][72], coalesced store
    ushort_t (*Ov)[72] = (ushort_t(*)[72])Ks;
#pragma unroll
    for (int ib = 0; ib < 2; ib++)
#pragma unroll
        for (int r = 0; r < 4; r++) {
            int i = ib * 16 + quad * 4 + r;
            Ov[i][wave * 16 + l16] = f2bf(Oacc[ib][r] * linvLDS[i]);
        }
    __syncthreads();
    {
        int r = tid >> 3, c8 = tid & 7;
        *(bf16x8*)(Oout + (size_t)(qbase + r) * CDIM + hoff + c8 * 8) =
            *(const bf16x8*)&Ov[r][c8 * 8];
    }
}

extern "C" void kernel_launch(void* const* d_in, const int* in_sizes, int n_in,
                              void* d_out, int out_size, void* d_ws, size_t ws_size,
                              hipStream_t stream)
{
    const float* x   = (const float*)d_in[0];
    const int*   sim = (const int*)d_in[1];
    const float* Wq  = (const float*)d_in[2];
    const float* bq  = (const float*)d_in[3];
    const float* Wk  = (const float*)d_in[4];
    const float* bk  = (const float*)d_in[5];
    const float* Wv  = (const float*)d_in[6];
    const float* bv  = (const float*)d_in[7];
    const float* Wo  = (const float*)d_in[8];
    const float* bo  = (const float*)d_in[9];
    float* out = (float*)d_out;

    // ws layout (ushort units): xb(=ao) | q | k | vT | Wf | Wob | biasf(fp32)
    ushort_t* xb  = (ushort_t*)d_ws;
    ushort_t* q   = xb + SX;
    ushort_t* k   = q + SX;
    ushort_t* vT  = k + SX;
    ushort_t* Wf  = vT + SX;
    ushort_t* Wob = Wf + 3 * SW;
    float* biasf  = (float*)(Wob + SW);
    ushort_t* ao  = xb;   // xb dead after gemm_qkv

    dim3 blk(256);
    {
        long total4 = (long)(SX + 4 * SW + 3 * CDIM) / 4;
        int nb = (int)((total4 + 255) / 256);
        convert_all<<<nb, blk, 0, stream>>>(x, Wq, Wk, Wv, Wo, bq, bk, bv,
                                            xb, Wf, Wob, biasf);
    }
    {
        dim3 g(N_TOK / 128, (3 * CDIM) / 64);
        gemm_qkv<<<g, blk, 0, stream>>>(xb, Wf, biasf, q, k, vT);
    }
    {
        dim3 g(N_TOK / 32, NH);
        attn_kernel<<<g, blk, 0, stream>>>(q, k, vT, sim, ao);
    }
    {
        dim3 g(N_TOK / 64, CDIM / 64);
        gemm_out<<<g, blk, 0, stream>>>(ao, Wob, bo, out);
    }
}

// Round 9
// 238.067 us; speedup vs baseline: 1.3923x; 1.0579x over previous
//
#include <hip/hip_runtime.h>
#include <hip/hip_bf16.h>
#include <stdint.h>

#define N_TOK 4096
#define CDIM 768
#define NH 12
#define HD 64
#define SX (N_TOK * CDIM)
#define SW (CDIM * CDIM)

typedef __attribute__((ext_vector_type(8))) short bf16x8;
typedef __attribute__((ext_vector_type(4))) float f32x4;
typedef unsigned short ushort_t;
typedef unsigned int uint_t;

typedef const __attribute__((address_space(1))) void* as1_cvp;
typedef __attribute__((address_space(3))) void* as3_vp;
#define GLD16(g, s) __builtin_amdgcn_global_load_lds((as1_cvp)(g), (as3_vp)(s), 16, 0, 0)

__device__ inline ushort_t f2bf(float f) {
    union { float f; uint_t u; } c; c.f = f;
    uint_t u = (c.u + 0x7FFFu + ((c.u >> 16) & 1u)) >> 16;
    return (ushort_t)u;
}
__device__ inline uint_t pack_bf2(float a, float b) {
    union { __hip_bfloat162 v; uint_t u; } c;
    c.v = __float22bfloat162_rn(make_float2(a, b));
    return c.u;
}

// fp32 -> bf16 one-shot conversion of x, Wq|Wk|Wv (concat), Wo; bq|bk|bv concat fp32.
__global__ __launch_bounds__(256) void convert_all(
    const float* __restrict__ x,
    const float* __restrict__ Wq, const float* __restrict__ Wk,
    const float* __restrict__ Wv, const float* __restrict__ Wo,
    const float* __restrict__ bq, const float* __restrict__ bk, const float* __restrict__ bv,
    ushort_t* __restrict__ xb, ushort_t* __restrict__ Wf,
    ushort_t* __restrict__ Wob, float* __restrict__ biasf)
{
    long i = ((long)blockIdx.x * 256 + threadIdx.x) * 4;
    const float* src; ushort_t* dst; long off;
    if (i < SX)               { src = x;  dst = xb;          off = i; }
    else if (i < SX + SW)     { src = Wq; dst = Wf;          off = i - SX; }
    else if (i < SX + 2*SW)   { src = Wk; dst = Wf + SW;     off = i - SX - SW; }
    else if (i < SX + 3*SW)   { src = Wv; dst = Wf + 2*SW;   off = i - SX - 2*SW; }
    else if (i < SX + 4*SW)   { src = Wo; dst = Wob;         off = i - SX - 3*SW; }
    else if (i < SX + 4*SW + 3*CDIM) {
        long b = i - (SX + 4*SW);
        const float* bs = (b < CDIM) ? bq + b : (b < 2*CDIM) ? bk + (b - CDIM) : bv + (b - 2*CDIM);
        *(float4*)(biasf + b) = *(const float4*)bs;
        return;
    } else return;
    float4 v4 = *(const float4*)(src + off);
    uint2 st = { pack_bf2(v4.x, v4.y), pack_bf2(v4.z, v4.w) };
    *(uint2*)(dst + off) = st;
}

// Fused QKV GEMM: 128x64 tiles (1152 blocks), BK=64, GLD16 staging, XOR-swizzled LDS.
// out[i][j] = sum_c xb[i][c]*Wf[j][c] + biasf[j]. j<768 -> q (PRE-SCALED by C1 for
// softmax exp2 folding); j<1536 -> k; else v stored transposed vT[j][i].
__global__ __launch_bounds__(256) void gemm_qkv(
    const ushort_t* __restrict__ xb, const ushort_t* __restrict__ Wf,
    const float* __restrict__ biasf,
    ushort_t* __restrict__ q, ushort_t* __restrict__ k, ushort_t* __restrict__ vT)
{
    __shared__ __align__(16) ushort_t Asm[128 * 64];
    __shared__ __align__(16) ushort_t Bsm[64 * 64];
    const int tid = threadIdx.x;
    const int w = tid >> 6, lane = tid & 63;
    const int quad = lane >> 4, l16 = lane & 15;
    const int row0 = blockIdx.x * 128;
    const int col0 = blockIdx.y * 64;
    const int rw = w * 32;
    const int srow = lane >> 3;
    const int sc = ((lane & 7) ^ srow) * 8;
    const int swz = l16 & 7;
    const float C1 = 0.18033688011112042f;   // 0.125 * log2(e)

    f32x4 acc[2][4];
#pragma unroll
    for (int a = 0; a < 2; a++)
#pragma unroll
        for (int b = 0; b < 4; b++) acc[a][b] = (f32x4){0.f, 0.f, 0.f, 0.f};

    for (int kc = 0; kc < CDIM; kc += 64) {
        __syncthreads();
#pragma unroll
        for (int c = 0; c < 4; c++) {
            int ra = w * 32 + c * 8;
            GLD16(xb + (size_t)(row0 + ra + srow) * CDIM + kc + sc, &Asm[ra * 64]);
        }
#pragma unroll
        for (int c = 0; c < 2; c++) {
            int rb_ = w * 16 + c * 8;
            GLD16(Wf + (size_t)(col0 + rb_ + srow) * CDIM + kc + sc, &Bsm[rb_ * 64]);
        }
        __syncthreads();
#pragma unroll
        for (int kk = 0; kk < 2; kk++) {
            const int po = ((kk * 4 + quad) ^ swz) * 8;
            bf16x8 af[2], bfr[4];
#pragma unroll
            for (int rb = 0; rb < 2; rb++)
                af[rb] = *(const bf16x8*)&Asm[(rw + rb * 16 + l16) * 64 + po];
#pragma unroll
            for (int cb = 0; cb < 4; cb++)
                bfr[cb] = *(const bf16x8*)&Bsm[(cb * 16 + l16) * 64 + po];
#pragma unroll
            for (int rb = 0; rb < 2; rb++)
#pragma unroll
                for (int cb = 0; cb < 4; cb++)
                    acc[rb][cb] = __builtin_amdgcn_mfma_f32_16x16x32_bf16(af[rb], bfr[cb], acc[rb][cb], 0, 0, 0);
        }
    }

    if (col0 < 2 * CDIM) {
        const bool isQ = (col0 < CDIM);
        ushort_t* dst = isQ ? q : k;
        const int jb0 = isQ ? col0 : col0 - CDIM;
        const float scale = isQ ? C1 : 1.0f;
#pragma unroll
        for (int cb = 0; cb < 4; cb++) {
            int j = jb0 + cb * 16 + l16;
            float bv_ = biasf[col0 + cb * 16 + l16];
#pragma unroll
            for (int rb = 0; rb < 2; rb++)
#pragma unroll
                for (int r = 0; r < 4; r++) {
                    int i = row0 + rw + rb * 16 + quad * 4 + r;
                    dst[(size_t)i * CDIM + j] = f2bf((acc[rb][cb][r] + bv_) * scale);
                }
        }
    } else {
        // vT: 64j x 128i transpose through Asm (swizzled), coalesced stores
        const int jv0 = col0 - 2 * CDIM;
        ushort_t* T = Asm;
        __syncthreads();
#pragma unroll
        for (int cb = 0; cb < 4; cb++) {
            int jl = cb * 16 + l16;
            float bv_ = biasf[col0 + jl];
#pragma unroll
            for (int rb = 0; rb < 2; rb++)
#pragma unroll
                for (int r = 0; r < 4; r++) {
                    int i = rw + rb * 16 + quad * 4 + r;
                    T[jl * 128 + (((i >> 3) ^ (jl & 7)) * 8) + (i & 7)] =
                        f2bf(acc[rb][cb][r] + bv_);
                }
        }
        __syncthreads();
#pragma unroll
        for (int p = 0; p < 4; p++) {
            int t = tid + p * 256, jl = t >> 4, i8 = t & 15;
            *(bf16x8*)(vT + (size_t)(jv0 + jl) * N_TOK + row0 + i8 * 8) =
                *(const bf16x8*)&T[jl * 128 + ((i8 ^ (jl & 7)) * 8)];
        }
    }
}

// Output projection: 64x64 tiles (768 blocks = 3/CU balanced). fp32 out.
__global__ __launch_bounds__(256) void gemm_out(
    const ushort_t* __restrict__ A, const ushort_t* __restrict__ W,
    const float* __restrict__ bias, float* __restrict__ out)
{
    __shared__ __align__(16) ushort_t Asm[64 * 64];
    __shared__ __align__(16) ushort_t Bsm[64 * 64];
    const int tid = threadIdx.x;
    const int w = tid >> 6, lane = tid & 63;
    const int quad = lane >> 4, l16 = lane & 15;
    const int row0 = blockIdx.x * 64;
    const int col0 = blockIdx.y * 64;
    const int srow = lane >> 3;
    const int sc = ((lane & 7) ^ srow) * 8;
    const int swz = l16 & 7;

    f32x4 acc[4];
#pragma unroll
    for (int b = 0; b < 4; b++) acc[b] = (f32x4){0.f, 0.f, 0.f, 0.f};

    for (int kc = 0; kc < CDIM; kc += 64) {
        __syncthreads();
#pragma unroll
        for (int c = 0; c < 2; c++) {
            int ra = w * 16 + c * 8;
            GLD16(A + (size_t)(row0 + ra + srow) * CDIM + kc + sc, &Asm[ra * 64]);
            GLD16(W + (size_t)(col0 + ra + srow) * CDIM + kc + sc, &Bsm[ra * 64]);
        }
        __syncthreads();
#pragma unroll
        for (int kk = 0; kk < 2; kk++) {
            const int po = ((kk * 4 + quad) ^ swz) * 8;
            bf16x8 af = *(const bf16x8*)&Asm[(w * 16 + l16) * 64 + po];
#pragma unroll
            for (int cb = 0; cb < 4; cb++) {
                bf16x8 bfr = *(const bf16x8*)&Bsm[(cb * 16 + l16) * 64 + po];
                acc[cb] = __builtin_amdgcn_mfma_f32_16x16x32_bf16(af, bfr, acc[cb], 0, 0, 0);
            }
        }
    }
#pragma unroll
    for (int cb = 0; cb < 4; cb++) {
        int j = col0 + cb * 16 + l16;
        float bv_ = bias[j];
#pragma unroll
        for (int r = 0; r < 4; r++) {
            int i = row0 + w * 16 + quad * 4 + r;
            out[(size_t)i * CDIM + j] = acc[cb][r] + bv_;
        }
    }
}

// Flash attention v5: v4 structure (32 q-rows/block, 1536 blocks, single-buffered
// GLD16 staging, 3 barriers/tile) with a VALU diet:
//  - raw v_exp_f32 via __builtin_amdgcn_exp2f (args bounded, no range fixup needed)
//  - all tile-invariant LDS addresses hoisted out of the j-loop
//  - GLD16 global addresses as incremented pointers (no per-tile 64-bit mul)
__global__ __launch_bounds__(256, 6) void attn_kernel(
    const ushort_t* __restrict__ Q, const ushort_t* __restrict__ K,
    const ushort_t* __restrict__ VT, const int* __restrict__ sim,
    ushort_t* __restrict__ Oout)
{
    __shared__ __align__(16) ushort_t Ks[64 * 64];   // j rows; reused as O tile
    __shared__ __align__(16) ushort_t Vts[64 * 64];  // d rows
    __shared__ __align__(16) ushort_t P2[32 * 64];   // i rows, swizzled
    __shared__ int ssim[32][12];
    __shared__ float psum[4][32];
    __shared__ float linvLDS[32];

    const int tid = threadIdx.x;
    const int wave = tid >> 6, lane = tid & 63;
    const int quad = lane >> 4, l16 = lane & 15;
    const int qbase = blockIdx.x * 32;
    const int hoff = blockIdx.y * HD;
    const float LOG2E = 1.4426950408889634f;

    const int srow = lane >> 3;
    const int sc = ((lane & 7) ^ srow) * 8;
    const int swz = l16 & 7;

    // Q fragments per-lane from global (tile-invariant B-operands)
    bf16x8 qf[2][2];
#pragma unroll
    for (int ib = 0; ib < 2; ib++)
#pragma unroll
        for (int kk = 0; kk < 2; kk++)
            qf[ib][kk] = *(const bf16x8*)(Q + (size_t)(qbase + ib * 16 + l16) * CDIM
                                          + hoff + kk * 32 + quad * 8);

    // sorted per-row bias indices (32 rows)
    if (tid < 32) {
        int vb_[10];
        const int* sp = sim + (size_t)(qbase + tid) * 10;
#pragma unroll
        for (int e = 0; e < 10; e++) vb_[e] = sp[e];
#pragma unroll
        for (int round = 0; round < 10; round++)
#pragma unroll
            for (int i = (round & 1); i + 1 < 10; i += 2) {
                int a = vb_[i], b = vb_[i + 1];
                vb_[i] = min(a, b); vb_[i + 1] = max(a, b);
            }
#pragma unroll
        for (int e = 0; e < 10; e++) ssim[tid][e] = vb_[e];
        ssim[tid][10] = 0x7FFFFFFF;
        ssim[tid][11] = 0x7FFFFFFF;
    }
    __syncthreads();

    // ---- hoisted tile-invariant addresses ----
    // staging DMA sources (advance per tile)
    const ushort_t* kg0 = K + (size_t)(wave * 16 + srow) * CDIM + hoff + sc;
    const ushort_t* kg1 = K + (size_t)(wave * 16 + 8 + srow) * CDIM + hoff + sc;
    const ushort_t* vg0 = VT + (size_t)(hoff + wave * 16 + srow) * N_TOK + sc;
    const ushort_t* vg1 = VT + (size_t)(hoff + wave * 16 + 8 + srow) * N_TOK + sc;
    ushort_t* ksd0 = &Ks[(wave * 16) * 64];
    ushort_t* ksd1 = &Ks[(wave * 16 + 8) * 64];
    ushort_t* vtd0 = &Vts[(wave * 16) * 64];
    ushort_t* vtd1 = &Vts[(wave * 16 + 8) * 64];
    // K / V fragment reads (LDS, constant addresses)
    const ushort_t* kfp[2];
    const ushort_t* vfp[2];
#pragma unroll
    for (int kk = 0; kk < 2; kk++) {
        int po = ((kk * 4 + quad) ^ swz) * 8;
        kfp[kk] = &Ks[(wave * 16 + l16) * 64 + po];
        vfp[kk] = &Vts[(wave * 16 + l16) * 64 + po];
    }
    // P2 write (2 per ib) and read (2 kk x 2 ib) addresses
    ushort_t* p2w[2];
    const ushort_t* p2r[2][2];
#pragma unroll
    for (int ib = 0; ib < 2; ib++) {
        int i = ib * 16 + l16;
        int cj = wave * 2 + (quad >> 1);
        p2w[ib] = &P2[i * 64 + (cj ^ (i & 7)) * 8 + (quad & 1) * 4];
#pragma unroll
        for (int kk = 0; kk < 2; kk++)
            p2r[kk][ib] = &P2[i * 64 + (((kk * 4 + quad) ^ (i & 7)) * 8)];
    }

    int curv[2], ptrv[2];
    float lsum[2] = { 0.f, 0.f };
    const int* srow0 = &ssim[l16][0];
    const int* srow1 = &ssim[16 + l16][0];
#pragma unroll
    for (int ib = 0; ib < 2; ib++) {
        ptrv[ib] = 0;
        curv[ib] = (ib ? srow1 : srow0)[0];
    }
    f32x4 Oacc[2];
#pragma unroll
    for (int a = 0; a < 2; a++) Oacc[a] = (f32x4){0.f, 0.f, 0.f, 0.f};

    for (int j0 = 0; j0 < N_TOK; j0 += 64) {
        __syncthreads();   // B0: prior tile's Ks/Vts/P2 reads complete (WAR)
        GLD16(kg0, ksd0); GLD16(kg1, ksd1);
        GLD16(vg0, vtd0); GLD16(vg1, vtd1);
        kg0 += 64 * CDIM; kg1 += 64 * CDIM;
        vg0 += 64;        vg1 += 64;
        __syncthreads();   // B1: staging visible

        // S^T = K.Q'^T : D[m=j16 (this wave)][n=i32]
        f32x4 sacc[2];
#pragma unroll
        for (int a = 0; a < 2; a++) sacc[a] = (f32x4){0.f, 0.f, 0.f, 0.f};
#pragma unroll
        for (int kk = 0; kk < 2; kk++) {
            bf16x8 ka = *(const bf16x8*)kfp[kk];
#pragma unroll
            for (int ib = 0; ib < 2; ib++)
                sacc[ib] = __builtin_amdgcn_mfma_f32_16x16x32_bf16(ka, qf[ib][kk], sacc[ib], 0, 0, 0);
        }

        // per-lane sparse-bias walk: +log2(e) per hit (duplicates accumulate)
        const int jend = j0 + 64;
#pragma unroll
        for (int ib = 0; ib < 2; ib++) {
            int cu = curv[ib], pt = ptrv[ib];
            const int* sr = ib ? srow1 : srow0;
            while (cu < jend) {
                int c = cu - j0;
                if ((c >> 4) == wave && ((c >> 2) & 3) == quad) {
                    int rr = c & 3;
                    sacc[ib][0] += (rr == 0) ? LOG2E : 0.f;
                    sacc[ib][1] += (rr == 1) ? LOG2E : 0.f;
                    sacc[ib][2] += (rr == 2) ? LOG2E : 0.f;
                    sacc[ib][3] += (rr == 3) ? LOG2E : 0.f;
                }
                pt++;
                cu = sr[pt];
            }
            curv[ib] = cu; ptrv[ib] = pt;
        }

        // P = raw v_exp_f32(s'); pack; swizzled b64 store into P2
#pragma unroll
        for (int ib = 0; ib < 2; ib++) {
            float e0 = __builtin_amdgcn_exp2f(sacc[ib][0]);
            float e1 = __builtin_amdgcn_exp2f(sacc[ib][1]);
            float e2 = __builtin_amdgcn_exp2f(sacc[ib][2]);
            float e3 = __builtin_amdgcn_exp2f(sacc[ib][3]);
            lsum[ib] += (e0 + e1) + (e2 + e3);
            uint2 pk = { pack_bf2(e0, e1), pack_bf2(e2, e3) };
            *(uint2*)p2w[ib] = pk;
        }
        __syncthreads();   // B2: P2 visible

        // O = P.V : D[m=i32][n=d16 (this wave)]
#pragma unroll
        for (int kk = 0; kk < 2; kk++) {
            bf16x8 vf = *(const bf16x8*)vfp[kk];
#pragma unroll
            for (int ib = 0; ib < 2; ib++) {
                bf16x8 pf = *(const bf16x8*)p2r[kk][ib];
                Oacc[ib] = __builtin_amdgcn_mfma_f32_16x16x32_bf16(pf, vf, Oacc[ib], 0, 0, 0);
            }
        }
    }

    // l: quad-reduce in-wave, combine 4 waves (j-slices) via LDS
#pragma unroll
    for (int ib = 0; ib < 2; ib++) {
        float l = lsum[ib];
        l += __shfl_xor(l, 16, 64);
        l += __shfl_xor(l, 32, 64);
        if (quad == 0) psum[wave][ib * 16 + l16] = l;
    }
    __syncthreads();
    if (tid < 32)
        linvLDS[tid] = 1.0f / (psum[0][tid] + psum[1][tid] + psum[2][tid] + psum[3][tid]);
    __syncthreads();

    // epilogue: scale, stage O tile into Ks as [32][72], coalesced store
    ushort_t (*Ov)[72] = (ushort_t(*)[72])Ks;
#pragma unroll
    for (int ib = 0; ib < 2; ib++)
#pragma unroll
        for (int r = 0; r < 4; r++) {
            int i = ib * 16 + quad * 4 + r;
            Ov[i][wave * 16 + l16] = f2bf(Oacc[ib][r] * linvLDS[i]);
        }
    __syncthreads();
    {
        int r = tid >> 3, c8 = tid & 7;
        *(bf16x8*)(Oout + (size_t)(qbase + r) * CDIM + hoff + c8 * 8) =
            *(const bf16x8*)&Ov[r][c8 * 8];
    }
}

extern "C" void kernel_launch(void* const* d_in, const int* in_sizes, int n_in,
                              void* d_out, int out_size, void* d_ws, size_t ws_size,
                              hipStream_t stream)
{
    const float* x   = (const float*)d_in[0];
    const int*   sim = (const int*)d_in[1];
    const float* Wq  = (const float*)d_in[2];
    const float* bq  = (const float*)d_in[3];
    const float* Wk  = (const float*)d_in[4];
    const float* bk  = (const float*)d_in[5];
    const float* Wv  = (const float*)d_in[6];
    const float* bv  = (const float*)d_in[7];
    const float* Wo  = (const float*)d_in[8];
    const float* bo  = (const float*)d_in[9];
    float* out = (float*)d_out;

    // ws layout (ushort units): xb(=ao) | q | k | vT | Wf | Wob | biasf(fp32)
    ushort_t* xb  = (ushort_t*)d_ws;
    ushort_t* q   = xb + SX;
    ushort_t* k   = q + SX;
    ushort_t* vT  = k + SX;
    ushort_t* Wf  = vT + SX;
    ushort_t* Wob = Wf + 3 * SW;
    float* biasf  = (float*)(Wob + SW);
    ushort_t* ao  = xb;   // xb dead after gemm_qkv

    dim3 blk(256);
    {
        long total4 = (long)(SX + 4 * SW + 3 * CDIM) / 4;
        int nb = (int)((total4 + 255) / 256);
        convert_all<<<nb, blk, 0, stream>>>(x, Wq, Wk, Wv, Wo, bq, bk, bv,
                                            xb, Wf, Wob, biasf);
    }
    {
        dim3 g(N_TOK / 128, (3 * CDIM) / 64);
        gemm_qkv<<<g, blk, 0, stream>>>(xb, Wf, biasf, q, k, vT);
    }
    {
        dim3 g(N_TOK / 32, NH);
        attn_kernel<<<g, blk, 0, stream>>>(q, k, vT, sim, ao);
    }
    {
        dim3 g(N_TOK / 64, CDIM / 64);
        gemm_out<<<g, blk, 0, stream>>>(ao, Wob, bo, out);
    }
}